// Round 6
// baseline (316.943 us; speedup 1.0000x reference)
//
#include <hip/hip_runtime.h>
#include <hip/hip_bf16.h>
#include <math.h>

#define BB 4
#define TT 2048
#define CC 768
#define HH 12
#define HDIM 64
#define C4 3072
#define MM (BB*TT)   // 8192 rows
#define EPSL 1e-5f

typedef __bf16 bf16x8 __attribute__((ext_vector_type(8)));
typedef float f32x4 __attribute__((ext_vector_type(4)));

__device__ __forceinline__ ushort f2bf(float f) {
    union { float f; unsigned u; } v; v.f = f;
    unsigned r = v.u + 0x7fffu + ((v.u >> 16) & 1u);
    return (ushort)(r >> 16);
}

__device__ __forceinline__ void glds16(const void* g, void* l) {
    __builtin_amdgcn_global_load_lds(
        (const __attribute__((address_space(1))) void*)g,
        (__attribute__((address_space(3))) void*)l, 16, 0, 0);
}

#define WVM(N) asm volatile("s_waitcnt vmcnt(" #N ")" ::: "memory")
#define WLG0   asm volatile("s_waitcnt lgkmcnt(0)" ::: "memory")

__device__ __forceinline__ void pbar() {
    __builtin_amdgcn_sched_barrier(0);
    __builtin_amdgcn_s_barrier();
    __builtin_amdgcn_sched_barrier(0);
}

// ---------------------------------------------------------------------------
// LayerNorm: one block per row, fp32 in -> bf16 out
// ---------------------------------------------------------------------------
__global__ __launch_bounds__(256) void ln_k(const float* __restrict__ X,
                                            const float* __restrict__ G,
                                            const float* __restrict__ Be,
                                            ushort* __restrict__ O)
{
    int row = blockIdx.x;
    const float* xr = X + (size_t)row * CC;
    int t = threadIdx.x;
    float v0 = xr[t], v1 = xr[t + 256], v2 = xr[t + 512];
    float s  = v0 + v1 + v2;
    float sq = v0*v0 + v1*v1 + v2*v2;
    #pragma unroll
    for (int off = 32; off; off >>= 1) {
        s  += __shfl_xor(s,  off);
        sq += __shfl_xor(sq, off);
    }
    __shared__ float red[8];
    int wv = t >> 6, ln = t & 63;
    if (ln == 0) { red[wv] = s; red[4 + wv] = sq; }
    __syncthreads();
    s  = red[0] + red[1] + red[2] + red[3];
    sq = red[4] + red[5] + red[6] + red[7];
    float mu  = s * (1.0f / CC);
    float var = sq * (1.0f / CC) - mu * mu;
    float rs  = rsqrtf(var + EPSL);
    ushort* orow = O + (size_t)row * CC;
    orow[t]       = f2bf((v0 - mu) * rs * G[t]       + Be[t]);
    orow[t + 256] = f2bf((v1 - mu) * rs * G[t + 256] + Be[t + 256]);
    orow[t + 512] = f2bf((v2 - mu) * rs * G[t + 512] + Be[t + 512]);
}

// ---------------------------------------------------------------------------
// Weight repack: fp32 W -> bf16 W^T [N][K] via 64x64 LDS transpose tile.
// MODE 0: W row-major [K,N].  MODE 1: W per-head [H][768][64] (wq/wk/wv).
// ---------------------------------------------------------------------------
template<int MODE>
__global__ __launch_bounds__(256) void repack_k(const float* __restrict__ W,
                                                ushort* __restrict__ WT,
                                                int K, int N, int outStride)
{
    __shared__ float tl[64][65];
    int n0 = blockIdx.x * 64, k0 = blockIdx.y * 64;
    int c = threadIdx.x & 63, rr = threadIdx.x >> 6;
    #pragma unroll
    for (int i = 0; i < 16; ++i) {
        int r = i * 4 + rr;
        float v;
        if (MODE == 0) v = W[(size_t)(k0 + r) * N + n0 + c];
        else           v = W[((size_t)(n0 >> 6) * CC + k0 + r) * 64 + c];
        tl[r][c] = v;
    }
    __syncthreads();
    #pragma unroll
    for (int i = 0; i < 16; ++i) {
        int r = i * 4 + rr;   // n within tile
        WT[(size_t)(n0 + r) * outStride + k0 + c] = f2bf(tl[c][r]);
    }
}

// ---------------------------------------------------------------------------
// 8-phase 256x256 bf16 MFMA GEMM (T1+T2+T3+T4+T5), BK=64, 512 threads,
// 8 waves (2M x 4N), per-wave 128x64 output, fp32 accum.
// LDS: 2 slots x (A[256][64] + B[256][64]) bf16 = 128 KiB, double-buffered.
// Stage units per tile: U1=B rows 0-127, U2=B rows 128-255,
//   U3=A rows {0-63,128-191}, U4=A rows {64-127,192-255}; one unit per phase,
//   staged one K-tile ahead. Waits: vmcnt(4) @p1, vmcnt(2) @p3 (never 0 in
//   steady state). LDS XOR swizzle: k-offset ^= (row&7)*8 elems, applied on
//   BOTH the pre-swizzled global_load_lds source and the ds_read address.
// EPI 1: QKV scatter -> bf16 q/k/v [B][H][T][64] (+per-segment bias)
// EPI 2: f32 out = acc + bias + resid
// EPI 3: bf16 out = relu(acc + bias)
// ---------------------------------------------------------------------------
template<int EPI>
__global__ __launch_bounds__(512, 2) void gemm8p(
    const ushort* __restrict__ A, const ushort* __restrict__ BT,
    int M, int N, int K,
    void* __restrict__ ov0, void* __restrict__ ov1, void* __restrict__ ov2,
    const float* __restrict__ bias0, const float* __restrict__ bias1,
    const float* __restrict__ bias2,
    const float* __restrict__ resid, ushort* __restrict__ obf)
{
    __shared__ ushort lds[2][2][256 * 64];   // [slot][0=A,1=B][row*64+col]

    int nbx = gridDim.x;
    int nwg = nbx * gridDim.y;
    int orig = blockIdx.y * nbx + blockIdx.x;
    int cpx = nwg >> 3;                       // all call sites: nwg % 8 == 0
    int swz = (orig & 7) * cpx + (orig >> 3);
    int bn = swz % nbx, bm = swz / nbx;

    int tid = threadIdx.x;
    int lane = tid & 63;
    int w = tid >> 6;
    int wrow = (w >> 2) * 128, wcol = (w & 3) * 64;
    int fr = lane & 15, kh = lane >> 4;
    int rxor = (fr & 7) * 8;                  // read-side swizzle (elements)

    const size_t aR0 = (size_t)bm * 256;
    const size_t bR0 = (size_t)bn * 256;
    const int nt = K >> 6;                    // >= 2 at all call sites

    int srow = tid >> 3;                      // staging row 0..63
    int scol = (tid & 7) * 8;                 // physical LDS col (elements)
    int gcol = scol ^ ((srow & 7) * 8);       // pre-swizzled logical k offset

    f32x4 acc[8][4] = {};

    // ---- prologue: stage all 4 units of tile 0 into slot 0 ----
    {
        glds16(BT + (bR0 +   0 + srow) * K + gcol, &lds[0][1][(  0 + srow) * 64 + scol]);
        glds16(BT + (bR0 +  64 + srow) * K + gcol, &lds[0][1][( 64 + srow) * 64 + scol]);
        glds16(BT + (bR0 + 128 + srow) * K + gcol, &lds[0][1][(128 + srow) * 64 + scol]);
        glds16(BT + (bR0 + 192 + srow) * K + gcol, &lds[0][1][(192 + srow) * 64 + scol]);
        glds16(A  + (aR0 +   0 + srow) * K + gcol, &lds[0][0][(  0 + srow) * 64 + scol]);
        glds16(A  + (aR0 + 128 + srow) * K + gcol, &lds[0][0][(128 + srow) * 64 + scol]);
        glds16(A  + (aR0 +  64 + srow) * K + gcol, &lds[0][0][( 64 + srow) * 64 + scol]);
        glds16(A  + (aR0 + 192 + srow) * K + gcol, &lds[0][0][(192 + srow) * 64 + scol]);
    }
    WVM(2);
    pbar();

    // ---- main loop: 4 phases per K-tile, 2 K-tiles in flight ----
    for (int t = 0; t < nt; ++t) {
        int slot = t & 1, nslot = slot ^ 1;
        int kst = (t + 1) << 6;
        bool st = (t + 1) < nt;
        const ushort* Asl = &lds[slot][0][0];
        const ushort* Bsl = &lds[slot][1][0];
        bf16x8 aF[4][2];
        #pragma unroll
        for (int p = 0; p < 4; ++p) {
            const int rh = p >> 1, ch = p & 1;
            // ds-reads for this phase's quadrant
            if (ch == 0) {
                #pragma unroll
                for (int i = 0; i < 4; ++i)
                    #pragma unroll
                    for (int k2 = 0; k2 < 2; ++k2) {
                        int R = wrow + rh * 64 + i * 16 + fr;
                        aF[i][k2] = *(const bf16x8*)&Asl[R * 64 + ((k2 * 32 + kh * 8) ^ rxor)];
                    }
            }
            bf16x8 bF[2][2];
            #pragma unroll
            for (int j2 = 0; j2 < 2; ++j2)
                #pragma unroll
                for (int k2 = 0; k2 < 2; ++k2) {
                    int Rb = wcol + ch * 32 + j2 * 16 + fr;
                    bF[j2][k2] = *(const bf16x8*)&Bsl[Rb * 64 + ((k2 * 32 + kh * 8) ^ rxor)];
                }
            // stage one unit of tile t+1 (2 x global_load_lds)
            if (st) {
                if (p == 0) {
                    glds16(BT + (bR0 +   0 + srow) * K + kst + gcol, &lds[nslot][1][(  0 + srow) * 64 + scol]);
                    glds16(BT + (bR0 +  64 + srow) * K + kst + gcol, &lds[nslot][1][( 64 + srow) * 64 + scol]);
                } else if (p == 1) {
                    glds16(BT + (bR0 + 128 + srow) * K + kst + gcol, &lds[nslot][1][(128 + srow) * 64 + scol]);
                    glds16(BT + (bR0 + 192 + srow) * K + kst + gcol, &lds[nslot][1][(192 + srow) * 64 + scol]);
                } else if (p == 2) {
                    glds16(A  + (aR0 +   0 + srow) * K + kst + gcol, &lds[nslot][0][(  0 + srow) * 64 + scol]);
                    glds16(A  + (aR0 + 128 + srow) * K + kst + gcol, &lds[nslot][0][(128 + srow) * 64 + scol]);
                } else {
                    glds16(A  + (aR0 +  64 + srow) * K + kst + gcol, &lds[nslot][0][( 64 + srow) * 64 + scol]);
                    glds16(A  + (aR0 + 192 + srow) * K + kst + gcol, &lds[nslot][0][(192 + srow) * 64 + scol]);
                }
            }
            // MFMA cluster (16)
            __builtin_amdgcn_s_setprio(1);
            #pragma unroll
            for (int i = 0; i < 4; ++i)
                #pragma unroll
                for (int j2 = 0; j2 < 2; ++j2)
                    #pragma unroll
                    for (int k2 = 0; k2 < 2; ++k2)
                        acc[rh * 4 + i][ch * 2 + j2] = __builtin_amdgcn_mfma_f32_16x16x32_bf16(
                            aF[i][k2], bF[j2][k2], acc[rh * 4 + i][ch * 2 + j2], 0, 0, 0);
            __builtin_amdgcn_s_setprio(0);
            // counted waits (ledger: p1 -> U4(t) ready; p3 -> U1..U3(t+1) ready)
            if (p == 1) { if (st) { WVM(4); } else { WVM(0); } }
            else if (p == 3) { WVM(2); }
            WLG0;
            pbar();
        }
    }

    // ---- epilogue: C/D layout col = lane&15, row = (lane>>4)*4 + r ----
    if (EPI == 1) {
        int seg = bn / 3;
        ushort* op = (ushort*)(seg == 0 ? ov0 : (seg == 1 ? ov1 : ov2));
        const float* bsp = seg == 0 ? bias0 : (seg == 1 ? bias1 : bias2);
        int cb = (bn - seg * 3) * 256 + wcol;    // multiple of 64
        int h = cb >> 6;
        #pragma unroll
        for (int ri = 0; ri < 8; ++ri) {
            int row0 = bm * 256 + wrow + ri * 16 + kh * 4;
            int b = row0 >> 11;
            int t0 = row0 & (TT - 1);
            #pragma unroll
            for (int cj = 0; cj < 4; ++cj) {
                int d = cj * 16 + fr;
                float bsv = bsp[h * 64 + d];
                #pragma unroll
                for (int r = 0; r < 4; ++r)
                    op[((size_t)(b * HH + h) * TT + t0 + r) * 64 + d] =
                        f2bf(acc[ri][cj][r] + bsv);
            }
        }
    } else if (EPI == 2) {
        float* o0 = (float*)ov0;
        #pragma unroll
        for (int ri = 0; ri < 8; ++ri) {
            int row0 = bm * 256 + wrow + ri * 16 + kh * 4;
            #pragma unroll
            for (int cj = 0; cj < 4; ++cj) {
                int col = bn * 256 + wcol + cj * 16 + fr;
                float bsv = bias0[col];
                #pragma unroll
                for (int r = 0; r < 4; ++r) {
                    size_t idx = (size_t)(row0 + r) * N + col;
                    o0[idx] = acc[ri][cj][r] + bsv + resid[idx];
                }
            }
        }
    } else {  // EPI 3
        #pragma unroll
        for (int ri = 0; ri < 8; ++ri) {
            int row0 = bm * 256 + wrow + ri * 16 + kh * 4;
            #pragma unroll
            for (int cj = 0; cj < 4; ++cj) {
                int col = bn * 256 + wcol + cj * 16 + fr;
                float bsv = bias0[col];
                #pragma unroll
                for (int r = 0; r < 4; ++r) {
                    float v = fmaxf(acc[ri][cj][r] + bsv, 0.f);
                    obf[(size_t)(row0 + r) * N + col] = f2bf(v);
                }
            }
        }
    }
}

// ---------------------------------------------------------------------------
// V transpose: bf16 [B,H,T,64] -> [B,H,64,T] (per (b,h), 64x64 LDS tiles)
// ---------------------------------------------------------------------------
__global__ __launch_bounds__(256) void vtrans_k(const ushort* __restrict__ V,
                                                ushort* __restrict__ Vt)
{
    __shared__ ushort tl[64][72];
    int blk = blockIdx.x;
    int tt = blk & 31, bh = blk >> 5;
    size_t base = (size_t)bh * TT * 64;
    int t0 = tt * 64;
    int e = threadIdx.x;
    int rr = e >> 3, cc8 = (e & 7) * 8;
    #pragma unroll
    for (int p = 0; p < 2; ++p) {
        int t = p * 32 + rr;
        *(uint4*)&tl[t][cc8] = *(const uint4*)&V[base + (size_t)(t0 + t) * 64 + cc8];
    }
    __syncthreads();
    #pragma unroll
    for (int p = 0; p < 2; ++p) {
        int d = p * 32 + rr;
        ushort tmp[8];
        #pragma unroll
        for (int i = 0; i < 8; ++i) tmp[i] = tl[cc8 + i][d];
        *(uint4*)&Vt[base + (size_t)d * TT + t0 + cc8] = *(uint4*)tmp;
    }
}

// ---------------------------------------------------------------------------
// Flash attention, bf16 MFMA, work-balanced (pair i,31-i => 33 tiles/block).
// Skip-max fast path; exact softmax either way. Q pre-scaled by log2(e).
// Deferred sum reduce. XCD swizzle for K/V L2 reuse.
// ---------------------------------------------------------------------------
__global__ __launch_bounds__(256) void attn_k(const ushort* __restrict__ Q,
                                              const ushort* __restrict__ Kb,
                                              const ushort* __restrict__ Vt,
                                              ushort* __restrict__ Ob)
{
    __shared__ ushort Kl[64][72];
    __shared__ ushort Vl[64][72];
    __shared__ ushort Pl[4][16][72];

    int orig = blockIdx.x;                 // nwg = 768
    int swz = (orig & 7) * 96 + (orig >> 3);
    int pair = swz & 15;
    int bh = swz >> 4;
    int b = bh / HH, h = bh - b * HH;
    int tid = threadIdx.x, lane = tid & 63, w = tid >> 6;
    int c = lane & 15, g = lane >> 4;
    size_t base = (size_t)bh * TT * 64;
    int srow = tid >> 3, scol = (tid & 7) * 8;
    const float LOG2E = 1.44269504088896340736f;

    #pragma unroll
    for (int sel = 0; sel < 2; ++sel) {
        int qt = sel ? (31 - pair) : pair;
        int q0 = qt * 64;

        bf16x8 aq[2];
        #pragma unroll
        for (int kc = 0; kc < 2; ++kc) {
            bf16x8 raw = *(const bf16x8*)&Q[base + (size_t)(q0 + w * 16 + c) * 64 + kc * 32 + g * 8];
            #pragma unroll
            for (int e = 0; e < 8; ++e)
                raw[e] = (__bf16)((float)raw[e] * LOG2E);
            aq[kc] = raw;
        }

        f32x4 oa[4] = {};
        float mrun[4] = {-INFINITY, -INFINITY, -INFINITY, -INFINITY};
        float lrun[4] = {0.f, 0.f, 0.f, 0.f};

        for (int kv0 = 0; kv0 <= q0; kv0 += 64) {
            __syncthreads();
            #pragma unroll
            for (int p = 0; p < 2; ++p) {
                int r = p * 32 + srow;
                *(uint4*)&Kl[r][scol] = *(const uint4*)&Kb[base + (size_t)(kv0 + r) * 64 + scol];
                *(uint4*)&Vl[r][scol] = *(const uint4*)&Vt[base + (size_t)r * TT + kv0 + scol];
            }
            __syncthreads();

            f32x4 sa[4] = {};
            #pragma unroll
            for (int kc = 0; kc < 2; ++kc)
                #pragma unroll
                for (int j = 0; j < 4; ++j) {
                    bf16x8 kf = *(const bf16x8*)&Kl[j * 16 + c][kc * 32 + g * 8];
                    sa[j] = __builtin_amdgcn_mfma_f32_16x16x32_bf16(aq[kc], kf, sa[j], 0, 0, 0);
                }

            if (kv0 == q0) {
                #pragma unroll
                for (int j = 0; j < 4; ++j)
                    #pragma unroll
                    for (int r = 0; r < 4; ++r)
                        if (j * 16 + c > w * 16 + g * 4 + r) sa[j][r] = -1e30f;
            }

            float vlmax = sa[0][0];
            #pragma unroll
            for (int j = 0; j < 4; ++j)
                #pragma unroll
                for (int r = 0; r < 4; ++r) vlmax = fmaxf(vlmax, sa[j][r]);
            float mmin = fminf(fminf(mrun[0], mrun[1]), fminf(mrun[2], mrun[3]));
            if (!__all(vlmax <= mmin + 11.5f)) {
                #pragma unroll
                for (int r = 0; r < 4; ++r) {
                    float m0 = fmaxf(fmaxf(sa[0][r], sa[1][r]), fmaxf(sa[2][r], sa[3][r]));
                    #pragma unroll
                    for (int off = 8; off; off >>= 1) m0 = fmaxf(m0, __shfl_xor(m0, off));
                    float mnew = fmaxf(mrun[r], m0);
                    float sc = __builtin_amdgcn_exp2f(mrun[r] - mnew);
                    lrun[r] *= sc;
                    #pragma unroll
                    for (int j = 0; j < 4; ++j) oa[j][r] *= sc;
                    mrun[r] = mnew;
                }
            }
            #pragma unroll
            for (int r = 0; r < 4; ++r) {
                float ps = 0.f;
                #pragma unroll
                for (int j = 0; j < 4; ++j) {
                    float p = __builtin_amdgcn_exp2f(sa[j][r] - mrun[r]);
                    sa[j][r] = p;
                    ps += p;
                }
                lrun[r] += ps;
            }

            #pragma unroll
            for (int r = 0; r < 4; ++r)
                #pragma unroll
                for (int j = 0; j < 4; ++j)
                    Pl[w][g * 4 + r][j * 16 + c] = (ushort)__builtin_bit_cast(unsigned short, (__bf16)sa[j][r]);

            bf16x8 pf[2];
            #pragma unroll
            for (int kc = 0; kc < 2; ++kc)
                pf[kc] = *(const bf16x8*)&Pl[w][c][kc * 32 + g * 8];

            #pragma unroll
            for (int kc = 0; kc < 2; ++kc)
                #pragma unroll
                for (int j = 0; j < 4; ++j) {
                    bf16x8 vf = *(const bf16x8*)&Vl[j * 16 + c][kc * 32 + g * 8];
                    oa[j] = __builtin_amdgcn_mfma_f32_16x16x32_bf16(pf[kc], vf, oa[j], 0, 0, 0);
                }
        }

        float inv[4];
        #pragma unroll
        for (int r = 0; r < 4; ++r) {
            float l = lrun[r];
            #pragma unroll
            for (int off = 8; off; off >>= 1) l += __shfl_xor(l, off);
            inv[r] = 1.0f / l;
        }
        size_t orow = (size_t)b * TT + q0 + w * 16;
        #pragma unroll
        for (int j = 0; j < 4; ++j)
            #pragma unroll
            for (int r = 0; r < 4; ++r) {
                float v = oa[j][r] * inv[r];
                Ob[(orow + g * 4 + r) * CC + h * 64 + j * 16 + c] = f2bf(v);
            }
    }
}

// ---------------------------------------------------------------------------
// Orchestration. ws layout (ushorts), S = MM*CC = 6291456:
//   WTqkv [2304*768]  WTp [768*768]  WT1 [3072*768]  WT2 [768*3072]
//   hbf [S]  attnb [S]  qb [S]  kb [S]  vb [S]  vtb [S]
//   midb [MM*3072] aliases qb..vtb exactly (dead after attention)
// ---------------------------------------------------------------------------
extern "C" void kernel_launch(void* const* d_in, const int* in_sizes, int n_in,
                              void* d_out, int out_size, void* d_ws, size_t ws_size,
                              hipStream_t stream)
{
    const float* x   = (const float*)d_in[0];
    const float* wq  = (const float*)d_in[1];
    const float* bq  = (const float*)d_in[2];
    const float* wk  = (const float*)d_in[3];
    const float* bk  = (const float*)d_in[4];
    const float* wvw = (const float*)d_in[5];
    const float* bv  = (const float*)d_in[6];
    const float* wp  = (const float*)d_in[7];
    const float* bp  = (const float*)d_in[8];
    const float* w1  = (const float*)d_in[9];
    const float* b1  = (const float*)d_in[10];
    const float* w2  = (const float*)d_in[11];
    const float* b2  = (const float*)d_in[12];
    const float* g1  = (const float*)d_in[13];
    const float* be1 = (const float*)d_in[14];
    const float* g2  = (const float*)d_in[15];
    const float* be2 = (const float*)d_in[16];

    float* out = (float*)d_out;
    const size_t S = (size_t)MM * CC;

    ushort* wsu   = (ushort*)d_ws;
    ushort* WTqkv = wsu;
    ushort* WTp   = WTqkv + (size_t)2304 * 768;
    ushort* WT1   = WTp   + (size_t)768 * 768;
    ushort* WT2   = WT1   + (size_t)3072 * 768;
    ushort* hbf   = WT2   + (size_t)768 * 3072;
    ushort* attnb = hbf   + S;
    ushort* qb    = attnb + S;
    ushort* kb    = qb + S;
    ushort* vb    = kb + S;
    ushort* vtb   = vb + S;
    ushort* midb  = qb;   // [8192][3072] bf16 == qb..vtb exactly

    dim3 rg(12, 12);
    repack_k<1><<<rg, 256, 0, stream>>>(wq,  WTqkv,                      768, 768, 768);
    repack_k<1><<<rg, 256, 0, stream>>>(wk,  WTqkv + (size_t)768*768,    768, 768, 768);
    repack_k<1><<<rg, 256, 0, stream>>>(wvw, WTqkv + (size_t)2*768*768,  768, 768, 768);
    repack_k<0><<<rg, 256, 0, stream>>>(wp,  WTp, 768, 768, 768);
    repack_k<0><<<dim3(48, 12), 256, 0, stream>>>(w1, WT1, 768, 3072, 768);
    repack_k<0><<<dim3(12, 48), 256, 0, stream>>>(w2, WT2, 3072, 768, 3072);

    // --- attention sublayer ---
    ln_k<<<MM, 256, 0, stream>>>(x, g1, be1, hbf);
    gemm8p<1><<<dim3(9, 32), 512, 0, stream>>>(hbf, WTqkv, MM, 2304, CC,
        qb, kb, vb, bq, bk, bv, nullptr, nullptr);
    vtrans_k<<<48 * 32, 256, 0, stream>>>(vb, vtb);
    attn_k<<<48 * 16, 256, 0, stream>>>(qb, kb, vtb, attnb);
    gemm8p<2><<<dim3(3, 32), 512, 0, stream>>>(attnb, WTp, MM, CC, CC,
        out, nullptr, nullptr, bp, nullptr, nullptr, x, nullptr);

    // --- MLP sublayer ---
    ln_k<<<MM, 256, 0, stream>>>(out, g2, be2, hbf);
    gemm8p<3><<<dim3(12, 32), 512, 0, stream>>>(hbf, WT1, MM, C4, CC,
        nullptr, nullptr, nullptr, b1, nullptr, nullptr, nullptr, midb);
    gemm8p<2><<<dim3(3, 32), 512, 0, stream>>>(midb, WT2, MM, CC, C4,
        out, nullptr, nullptr, b2, nullptr, nullptr, out, nullptr);
}

// Round 7
// 303.689 us; speedup vs baseline: 1.0436x; 1.0436x over previous
//
#include <hip/hip_runtime.h>
#include <hip/hip_bf16.h>
#include <math.h>

#define BB 4
#define TT 2048
#define CC 768
#define HH 12
#define HDIM 64
#define C4 3072
#define MM (BB*TT)   // 8192 rows
#define EPSL 1e-5f

typedef __bf16 bf16x8 __attribute__((ext_vector_type(8)));
typedef float f32x4 __attribute__((ext_vector_type(4)));

__device__ __forceinline__ ushort f2bf(float f) {
    union { float f; unsigned u; } v; v.f = f;
    unsigned r = v.u + 0x7fffu + ((v.u >> 16) & 1u);
    return (ushort)(r >> 16);
}

__device__ __forceinline__ void glds16(const void* g, void* l) {
    __builtin_amdgcn_global_load_lds(
        (const __attribute__((address_space(1))) void*)g,
        (__attribute__((address_space(3))) void*)l, 16, 0, 0);
}

#define WVM(N) asm volatile("s_waitcnt vmcnt(" #N ")" ::: "memory")
#define WLG0   asm volatile("s_waitcnt lgkmcnt(0)" ::: "memory")

__device__ __forceinline__ void pbar() {
    __builtin_amdgcn_sched_barrier(0);
    __builtin_amdgcn_s_barrier();
    __builtin_amdgcn_sched_barrier(0);
}

// ---------------------------------------------------------------------------
// LayerNorm: one block per row, fp32 in -> bf16 out
// ---------------------------------------------------------------------------
__global__ __launch_bounds__(256) void ln_k(const float* __restrict__ X,
                                            const float* __restrict__ G,
                                            const float* __restrict__ Be,
                                            ushort* __restrict__ O)
{
    int row = blockIdx.x;
    const float* xr = X + (size_t)row * CC;
    int t = threadIdx.x;
    float v0 = xr[t], v1 = xr[t + 256], v2 = xr[t + 512];
    float s  = v0 + v1 + v2;
    float sq = v0*v0 + v1*v1 + v2*v2;
    #pragma unroll
    for (int off = 32; off; off >>= 1) {
        s  += __shfl_xor(s,  off);
        sq += __shfl_xor(sq, off);
    }
    __shared__ float red[8];
    int wv = t >> 6, ln = t & 63;
    if (ln == 0) { red[wv] = s; red[4 + wv] = sq; }
    __syncthreads();
    s  = red[0] + red[1] + red[2] + red[3];
    sq = red[4] + red[5] + red[6] + red[7];
    float mu  = s * (1.0f / CC);
    float var = sq * (1.0f / CC) - mu * mu;
    float rs  = rsqrtf(var + EPSL);
    ushort* orow = O + (size_t)row * CC;
    orow[t]       = f2bf((v0 - mu) * rs * G[t]       + Be[t]);
    orow[t + 256] = f2bf((v1 - mu) * rs * G[t + 256] + Be[t + 256]);
    orow[t + 512] = f2bf((v2 - mu) * rs * G[t + 512] + Be[t + 512]);
}

// ---------------------------------------------------------------------------
// LayerNorm fused with split-K reduce: v = X + P (proj partial); X <- v;
// O <- bf16 LN(v). One block per row.
// ---------------------------------------------------------------------------
__global__ __launch_bounds__(256) void ln_add_k(float* __restrict__ X,
                                                const float* __restrict__ P,
                                                const float* __restrict__ G,
                                                const float* __restrict__ Be,
                                                ushort* __restrict__ O)
{
    int row = blockIdx.x;
    float* xr = X + (size_t)row * CC;
    const float* pr = P + (size_t)row * CC;
    int t = threadIdx.x;
    float v0 = xr[t]       + pr[t];
    float v1 = xr[t + 256] + pr[t + 256];
    float v2 = xr[t + 512] + pr[t + 512];
    xr[t] = v0; xr[t + 256] = v1; xr[t + 512] = v2;
    float s  = v0 + v1 + v2;
    float sq = v0*v0 + v1*v1 + v2*v2;
    #pragma unroll
    for (int off = 32; off; off >>= 1) {
        s  += __shfl_xor(s,  off);
        sq += __shfl_xor(sq, off);
    }
    __shared__ float red[8];
    int wv = t >> 6, ln = t & 63;
    if (ln == 0) { red[wv] = s; red[4 + wv] = sq; }
    __syncthreads();
    s  = red[0] + red[1] + red[2] + red[3];
    sq = red[4] + red[5] + red[6] + red[7];
    float mu  = s * (1.0f / CC);
    float var = sq * (1.0f / CC) - mu * mu;
    float rs  = rsqrtf(var + EPSL);
    ushort* orow = O + (size_t)row * CC;
    orow[t]       = f2bf((v0 - mu) * rs * G[t]       + Be[t]);
    orow[t + 256] = f2bf((v1 - mu) * rs * G[t + 256] + Be[t + 256]);
    orow[t + 512] = f2bf((v2 - mu) * rs * G[t + 512] + Be[t + 512]);
}

// ---------------------------------------------------------------------------
// Split-K reduce: o += p (fp32, float4 grid-stride)
// ---------------------------------------------------------------------------
__global__ __launch_bounds__(256) void addto_k(float* __restrict__ o,
                                               const float* __restrict__ p,
                                               int n4)
{
    int i = blockIdx.x * 256 + threadIdx.x;
    int stride = gridDim.x * 256;
    for (; i < n4; i += stride) {
        float4 a = ((const float4*)o)[i];
        float4 b = ((const float4*)p)[i];
        a.x += b.x; a.y += b.y; a.z += b.z; a.w += b.w;
        ((float4*)o)[i] = a;
    }
}

// ---------------------------------------------------------------------------
// Weight repack: fp32 W -> bf16 W^T [N][K] via 64x64 LDS transpose tile.
// MODE 0: W row-major [K,N].  MODE 1: W per-head [H][768][64] (wq/wk/wv).
// ---------------------------------------------------------------------------
template<int MODE>
__global__ __launch_bounds__(256) void repack_k(const float* __restrict__ W,
                                                ushort* __restrict__ WT,
                                                int K, int N, int outStride)
{
    __shared__ float tl[64][65];
    int n0 = blockIdx.x * 64, k0 = blockIdx.y * 64;
    int c = threadIdx.x & 63, rr = threadIdx.x >> 6;
    #pragma unroll
    for (int i = 0; i < 16; ++i) {
        int r = i * 4 + rr;
        float v;
        if (MODE == 0) v = W[(size_t)(k0 + r) * N + n0 + c];
        else           v = W[((size_t)(n0 >> 6) * CC + k0 + r) * 64 + c];
        tl[r][c] = v;
    }
    __syncthreads();
    #pragma unroll
    for (int i = 0; i < 16; ++i) {
        int r = i * 4 + rr;   // n within tile
        WT[(size_t)(n0 + r) * outStride + k0 + c] = f2bf(tl[c][r]);
    }
}

// ---------------------------------------------------------------------------
// 8-phase 256x256 bf16 MFMA GEMM, BK=64, 512 threads, 8 waves (2Mx4N),
// per-wave 128x64 output, fp32 accum. LDS 128 KiB double-buffered.
// Prefetch issue: U1,U2 (all B) at p0; U3,U4 (all A) at p1 -> every load has
// >=2 phases of slack before its wait. Waits: vmcnt(8)@p1 (forces U4(t),
// issued 4 phases back), vmcnt(2)@p3 (forces U1-U3(t+1), issued 2-3 back).
// Split-K via gridDim.z: z-block handles K/gridDim.z slice; z>0 writes raw
// fp32 partial to `part`, z==0 runs the EPI epilogue.
// LDS XOR swizzle on both glds-source and ds_read (verified r6, conflicts=0).
// ---------------------------------------------------------------------------
template<int EPI>
__global__ __launch_bounds__(512, 2) void gemm8p(
    const ushort* __restrict__ A, const ushort* __restrict__ BT,
    int M, int N, int K,
    void* __restrict__ ov0, void* __restrict__ ov1, void* __restrict__ ov2,
    const float* __restrict__ bias0, const float* __restrict__ bias1,
    const float* __restrict__ bias2,
    const float* __restrict__ resid, ushort* __restrict__ obf,
    float* __restrict__ part)
{
    __shared__ ushort lds[2][2][256 * 64];   // [slot][0=A,1=B][row*64+col]

    int nbx = gridDim.x;
    int nwg = nbx * gridDim.y * gridDim.z;
    int orig = (blockIdx.z * gridDim.y + blockIdx.y) * nbx + blockIdx.x;
    int cpx = nwg >> 3;                       // all call sites: nwg % 8 == 0
    int swz = (orig & 7) * cpx + (orig >> 3);
    int zi = swz / (nbx * gridDim.y);
    int rem = swz - zi * nbx * gridDim.y;
    int bn = rem % nbx, bm = rem / nbx;

    int tid = threadIdx.x;
    int lane = tid & 63;
    int w = tid >> 6;
    int wrow = (w >> 2) * 128, wcol = (w & 3) * 64;
    int fr = lane & 15, kh = lane >> 4;
    int rxor = (fr & 7) * 8;                  // read-side swizzle (elements)

    const size_t aR0 = (size_t)bm * 256;
    const size_t bR0 = (size_t)bn * 256;
    const int Ksl = K / (int)gridDim.z;
    const int koff = zi * Ksl;
    const int nt = Ksl >> 6;                  // >= 6 at all call sites

    int srow = tid >> 3;                      // staging row 0..63
    int scol = (tid & 7) * 8;                 // physical LDS col (elements)
    int gcol = koff + (scol ^ ((srow & 7) * 8));  // pre-swizzled global k off

    f32x4 acc[8][4] = {};

    // ---- prologue: stage all 4 units of tile 0 into slot 0 ----
    {
        glds16(BT + (bR0 +   0 + srow) * K + gcol, &lds[0][1][(  0 + srow) * 64 + scol]);
        glds16(BT + (bR0 +  64 + srow) * K + gcol, &lds[0][1][( 64 + srow) * 64 + scol]);
        glds16(BT + (bR0 + 128 + srow) * K + gcol, &lds[0][1][(128 + srow) * 64 + scol]);
        glds16(BT + (bR0 + 192 + srow) * K + gcol, &lds[0][1][(192 + srow) * 64 + scol]);
        glds16(A  + (aR0 +   0 + srow) * K + gcol, &lds[0][0][(  0 + srow) * 64 + scol]);
        glds16(A  + (aR0 + 128 + srow) * K + gcol, &lds[0][0][(128 + srow) * 64 + scol]);
        glds16(A  + (aR0 +  64 + srow) * K + gcol, &lds[0][0][( 64 + srow) * 64 + scol]);
        glds16(A  + (aR0 + 192 + srow) * K + gcol, &lds[0][0][(192 + srow) * 64 + scol]);
    }
    WVM(2);
    pbar();

    // ---- main loop: 4 phases per K-tile, prefetch 1 tile ahead ----
    for (int t = 0; t < nt; ++t) {
        int slot = t & 1, nslot = slot ^ 1;
        int kst = gcol + ((t + 1) << 6);
        bool st = (t + 1) < nt;
        const ushort* Asl = &lds[slot][0][0];
        const ushort* Bsl = &lds[slot][1][0];
        bf16x8 aF[4][2];
        #pragma unroll
        for (int p = 0; p < 4; ++p) {
            const int rh = p >> 1, ch = p & 1;
            // ds-reads for this phase's quadrant
            if (ch == 0) {
                #pragma unroll
                for (int i = 0; i < 4; ++i)
                    #pragma unroll
                    for (int k2 = 0; k2 < 2; ++k2) {
                        int R = wrow + rh * 64 + i * 16 + fr;
                        aF[i][k2] = *(const bf16x8*)&Asl[R * 64 + ((k2 * 32 + kh * 8) ^ rxor)];
                    }
            }
            bf16x8 bF[2][2];
            #pragma unroll
            for (int j2 = 0; j2 < 2; ++j2)
                #pragma unroll
                for (int k2 = 0; k2 < 2; ++k2) {
                    int Rb = wcol + ch * 32 + j2 * 16 + fr;
                    bF[j2][k2] = *(const bf16x8*)&Bsl[Rb * 64 + ((k2 * 32 + kh * 8) ^ rxor)];
                }
            // stage tile t+1: all B at p0, all A at p1 (max latency slack)
            if (st) {
                if (p == 0) {
                    glds16(BT + (bR0 +   0 + srow) * K + kst, &lds[nslot][1][(  0 + srow) * 64 + scol]);
                    glds16(BT + (bR0 +  64 + srow) * K + kst, &lds[nslot][1][( 64 + srow) * 64 + scol]);
                    glds16(BT + (bR0 + 128 + srow) * K + kst, &lds[nslot][1][(128 + srow) * 64 + scol]);
                    glds16(BT + (bR0 + 192 + srow) * K + kst, &lds[nslot][1][(192 + srow) * 64 + scol]);
                } else if (p == 1) {
                    glds16(A  + (aR0 +   0 + srow) * K + kst, &lds[nslot][0][(  0 + srow) * 64 + scol]);
                    glds16(A  + (aR0 + 128 + srow) * K + kst, &lds[nslot][0][(128 + srow) * 64 + scol]);
                    glds16(A  + (aR0 +  64 + srow) * K + kst, &lds[nslot][0][( 64 + srow) * 64 + scol]);
                    glds16(A  + (aR0 + 192 + srow) * K + kst, &lds[nslot][0][(192 + srow) * 64 + scol]);
                }
            }
            // MFMA cluster (16)
            __builtin_amdgcn_s_setprio(1);
            #pragma unroll
            for (int i = 0; i < 4; ++i)
                #pragma unroll
                for (int j2 = 0; j2 < 2; ++j2)
                    #pragma unroll
                    for (int k2 = 0; k2 < 2; ++k2)
                        acc[rh * 4 + i][ch * 2 + j2] = __builtin_amdgcn_mfma_f32_16x16x32_bf16(
                            aF[i][k2], bF[j2][k2], acc[rh * 4 + i][ch * 2 + j2], 0, 0, 0);
            __builtin_amdgcn_s_setprio(0);
            // counted waits (ledger: p1 -> U4(t) ready; p3 -> U1-U3(t+1) ready)
            if (p == 1) { if (st) { WVM(8); } else { WVM(0); } }
            else if (p == 3) { if (st) { WVM(2); } }
            WLG0;
            pbar();
        }
    }

    // ---- epilogue: C/D layout col = lane&15, row = (lane>>4)*4 + r ----
    if (gridDim.z > 1 && zi > 0) {
        // raw fp32 partial (no bias)
        #pragma unroll
        for (int ri = 0; ri < 8; ++ri) {
            int row0 = bm * 256 + wrow + ri * 16 + kh * 4;
            #pragma unroll
            for (int cj = 0; cj < 4; ++cj) {
                int col = bn * 256 + wcol + cj * 16 + fr;
                #pragma unroll
                for (int r = 0; r < 4; ++r)
                    part[(size_t)(row0 + r) * N + col] = acc[ri][cj][r];
            }
        }
    } else if (EPI == 1) {
        int seg = bn / 3;
        ushort* op = (ushort*)(seg == 0 ? ov0 : (seg == 1 ? ov1 : ov2));
        const float* bsp = seg == 0 ? bias0 : (seg == 1 ? bias1 : bias2);
        int cb = (bn - seg * 3) * 256 + wcol;    // multiple of 64
        int h = cb >> 6;
        #pragma unroll
        for (int ri = 0; ri < 8; ++ri) {
            int row0 = bm * 256 + wrow + ri * 16 + kh * 4;
            int b = row0 >> 11;
            int t0 = row0 & (TT - 1);
            #pragma unroll
            for (int cj = 0; cj < 4; ++cj) {
                int d = cj * 16 + fr;
                float bsv = bsp[h * 64 + d];
                #pragma unroll
                for (int r = 0; r < 4; ++r)
                    op[((size_t)(b * HH + h) * TT + t0 + r) * 64 + d] =
                        f2bf(acc[ri][cj][r] + bsv);
            }
        }
    } else if (EPI == 2) {
        float* o0 = (float*)ov0;
        #pragma unroll
        for (int ri = 0; ri < 8; ++ri) {
            int row0 = bm * 256 + wrow + ri * 16 + kh * 4;
            #pragma unroll
            for (int cj = 0; cj < 4; ++cj) {
                int col = bn * 256 + wcol + cj * 16 + fr;
                float bsv = bias0[col];
                #pragma unroll
                for (int r = 0; r < 4; ++r) {
                    size_t idx = (size_t)(row0 + r) * N + col;
                    o0[idx] = acc[ri][cj][r] + bsv + resid[idx];
                }
            }
        }
    } else {  // EPI 3
        #pragma unroll
        for (int ri = 0; ri < 8; ++ri) {
            int row0 = bm * 256 + wrow + ri * 16 + kh * 4;
            #pragma unroll
            for (int cj = 0; cj < 4; ++cj) {
                int col = bn * 256 + wcol + cj * 16 + fr;
                float bsv = bias0[col];
                #pragma unroll
                for (int r = 0; r < 4; ++r) {
                    float v = fmaxf(acc[ri][cj][r] + bsv, 0.f);
                    obf[(size_t)(row0 + r) * N + col] = f2bf(v);
                }
            }
        }
    }
}

// ---------------------------------------------------------------------------
// V transpose: bf16 [B,H,T,64] -> [B,H,64,T] (per (b,h), 64x64 LDS tiles)
// ---------------------------------------------------------------------------
__global__ __launch_bounds__(256) void vtrans_k(const ushort* __restrict__ V,
                                                ushort* __restrict__ Vt)
{
    __shared__ ushort tl[64][72];
    int blk = blockIdx.x;
    int tt = blk & 31, bh = blk >> 5;
    size_t base = (size_t)bh * TT * 64;
    int t0 = tt * 64;
    int e = threadIdx.x;
    int rr = e >> 3, cc8 = (e & 7) * 8;
    #pragma unroll
    for (int p = 0; p < 2; ++p) {
        int t = p * 32 + rr;
        *(uint4*)&tl[t][cc8] = *(const uint4*)&V[base + (size_t)(t0 + t) * 64 + cc8];
    }
    __syncthreads();
    #pragma unroll
    for (int p = 0; p < 2; ++p) {
        int d = p * 32 + rr;
        ushort tmp[8];
        #pragma unroll
        for (int i = 0; i < 8; ++i) tmp[i] = tl[cc8 + i][d];
        *(uint4*)&Vt[base + (size_t)d * TT + t0 + cc8] = *(uint4*)tmp;
    }
}

// ---------------------------------------------------------------------------
// Flash attention, bf16 MFMA, work-balanced (pair i,31-i => 33 tiles/block).
// Skip-max fast path; exact softmax either way. Q pre-scaled by log2(e).
// Deferred sum reduce. XCD swizzle for K/V L2 reuse.
// ---------------------------------------------------------------------------
__global__ __launch_bounds__(256) void attn_k(const ushort* __restrict__ Q,
                                              const ushort* __restrict__ Kb,
                                              const ushort* __restrict__ Vt,
                                              ushort* __restrict__ Ob)
{
    __shared__ ushort Kl[64][72];
    __shared__ ushort Vl[64][72];
    __shared__ ushort Pl[4][16][72];

    int orig = blockIdx.x;                 // nwg = 768
    int swz = (orig & 7) * 96 + (orig >> 3);
    int pair = swz & 15;
    int bh = swz >> 4;
    int b = bh / HH, h = bh - b * HH;
    int tid = threadIdx.x, lane = tid & 63, w = tid >> 6;
    int c = lane & 15, g = lane >> 4;
    size_t base = (size_t)bh * TT * 64;
    int srow = tid >> 3, scol = (tid & 7) * 8;
    const float LOG2E = 1.44269504088896340736f;

    #pragma unroll
    for (int sel = 0; sel < 2; ++sel) {
        int qt = sel ? (31 - pair) : pair;
        int q0 = qt * 64;

        bf16x8 aq[2];
        #pragma unroll
        for (int kc = 0; kc < 2; ++kc) {
            bf16x8 raw = *(const bf16x8*)&Q[base + (size_t)(q0 + w * 16 + c) * 64 + kc * 32 + g * 8];
            #pragma unroll
            for (int e = 0; e < 8; ++e)
                raw[e] = (__bf16)((float)raw[e] * LOG2E);
            aq[kc] = raw;
        }

        f32x4 oa[4] = {};
        float mrun[4] = {-INFINITY, -INFINITY, -INFINITY, -INFINITY};
        float lrun[4] = {0.f, 0.f, 0.f, 0.f};

        for (int kv0 = 0; kv0 <= q0; kv0 += 64) {
            __syncthreads();
            #pragma unroll
            for (int p = 0; p < 2; ++p) {
                int r = p * 32 + srow;
                *(uint4*)&Kl[r][scol] = *(const uint4*)&Kb[base + (size_t)(kv0 + r) * 64 + scol];
                *(uint4*)&Vl[r][scol] = *(const uint4*)&Vt[base + (size_t)r * TT + kv0 + scol];
            }
            __syncthreads();

            f32x4 sa[4] = {};
            #pragma unroll
            for (int kc = 0; kc < 2; ++kc)
                #pragma unroll
                for (int j = 0; j < 4; ++j) {
                    bf16x8 kf = *(const bf16x8*)&Kl[j * 16 + c][kc * 32 + g * 8];
                    sa[j] = __builtin_amdgcn_mfma_f32_16x16x32_bf16(aq[kc], kf, sa[j], 0, 0, 0);
                }

            if (kv0 == q0) {
                #pragma unroll
                for (int j = 0; j < 4; ++j)
                    #pragma unroll
                    for (int r = 0; r < 4; ++r)
                        if (j * 16 + c > w * 16 + g * 4 + r) sa[j][r] = -1e30f;
            }

            float vlmax = sa[0][0];
            #pragma unroll
            for (int j = 0; j < 4; ++j)
                #pragma unroll
                for (int r = 0; r < 4; ++r) vlmax = fmaxf(vlmax, sa[j][r]);
            float mmin = fminf(fminf(mrun[0], mrun[1]), fminf(mrun[2], mrun[3]));
            if (!__all(vlmax <= mmin + 11.5f)) {
                #pragma unroll
                for (int r = 0; r < 4; ++r) {
                    float m0 = fmaxf(fmaxf(sa[0][r], sa[1][r]), fmaxf(sa[2][r], sa[3][r]));
                    #pragma unroll
                    for (int off = 8; off; off >>= 1) m0 = fmaxf(m0, __shfl_xor(m0, off));
                    float mnew = fmaxf(mrun[r], m0);
                    float sc = __builtin_amdgcn_exp2f(mrun[r] - mnew);
                    lrun[r] *= sc;
                    #pragma unroll
                    for (int j = 0; j < 4; ++j) oa[j][r] *= sc;
                    mrun[r] = mnew;
                }
            }
            #pragma unroll
            for (int r = 0; r < 4; ++r) {
                float ps = 0.f;
                #pragma unroll
                for (int j = 0; j < 4; ++j) {
                    float p = __builtin_amdgcn_exp2f(sa[j][r] - mrun[r]);
                    sa[j][r] = p;
                    ps += p;
                }
                lrun[r] += ps;
            }

            #pragma unroll
            for (int r = 0; r < 4; ++r)
                #pragma unroll
                for (int j = 0; j < 4; ++j)
                    Pl[w][g * 4 + r][j * 16 + c] = (ushort)__builtin_bit_cast(unsigned short, (__bf16)sa[j][r]);

            bf16x8 pf[2];
            #pragma unroll
            for (int kc = 0; kc < 2; ++kc)
                pf[kc] = *(const bf16x8*)&Pl[w][c][kc * 32 + g * 8];

            #pragma unroll
            for (int kc = 0; kc < 2; ++kc)
                #pragma unroll
                for (int j = 0; j < 4; ++j) {
                    bf16x8 vf = *(const bf16x8*)&Vl[j * 16 + c][kc * 32 + g * 8];
                    oa[j] = __builtin_amdgcn_mfma_f32_16x16x32_bf16(pf[kc], vf, oa[j], 0, 0, 0);
                }
        }

        float inv[4];
        #pragma unroll
        for (int r = 0; r < 4; ++r) {
            float l = lrun[r];
            #pragma unroll
            for (int off = 8; off; off >>= 1) l += __shfl_xor(l, off);
            inv[r] = 1.0f / l;
        }
        size_t orow = (size_t)b * TT + q0 + w * 16;
        #pragma unroll
        for (int j = 0; j < 4; ++j)
            #pragma unroll
            for (int r = 0; r < 4; ++r) {
                float v = oa[j][r] * inv[r];
                Ob[(orow + g * 4 + r) * CC + h * 64 + j * 16 + c] = f2bf(v);
            }
    }
}

// ---------------------------------------------------------------------------
// Orchestration. ws layout (ushorts), S = MM*CC = 6291456:
//   WTqkv [2304*768]  WTp [768*768]  WT1 [3072*768]  WT2 [768*3072]
//   hbf [S]  attnb [S]  qb [S]  kb [S]  vb [S]  vtb [S]
//   midb [MM*3072] aliases qb..vtb (dead after attention)
//   part_proj f32 [MM*768] aliases qb+kb (dead after attn; freed before w1)
//   part_w2   f32 [MM*768] aliases hbf+attnb (dead after w1)
// ---------------------------------------------------------------------------
extern "C" void kernel_launch(void* const* d_in, const int* in_sizes, int n_in,
                              void* d_out, int out_size, void* d_ws, size_t ws_size,
                              hipStream_t stream)
{
    const float* x   = (const float*)d_in[0];
    const float* wq  = (const float*)d_in[1];
    const float* bq  = (const float*)d_in[2];
    const float* wk  = (const float*)d_in[3];
    const float* bk  = (const float*)d_in[4];
    const float* wvw = (const float*)d_in[5];
    const float* bv  = (const float*)d_in[6];
    const float* wp  = (const float*)d_in[7];
    const float* bp  = (const float*)d_in[8];
    const float* w1  = (const float*)d_in[9];
    const float* b1  = (const float*)d_in[10];
    const float* w2  = (const float*)d_in[11];
    const float* b2  = (const float*)d_in[12];
    const float* g1  = (const float*)d_in[13];
    const float* be1 = (const float*)d_in[14];
    const float* g2  = (const float*)d_in[15];
    const float* be2 = (const float*)d_in[16];

    float* out = (float*)d_out;
    const size_t S = (size_t)MM * CC;

    ushort* wsu   = (ushort*)d_ws;
    ushort* WTqkv = wsu;
    ushort* WTp   = WTqkv + (size_t)2304 * 768;
    ushort* WT1   = WTp   + (size_t)768 * 768;
    ushort* WT2   = WT1   + (size_t)3072 * 768;
    ushort* hbf   = WT2   + (size_t)768 * 3072;
    ushort* attnb = hbf   + S;
    ushort* qb    = attnb + S;
    ushort* kb    = qb + S;
    ushort* vb    = kb + S;
    ushort* vtb   = vb + S;
    ushort* midb  = qb;                 // [8192][3072] bf16 == qb..vtb
    float*  part_proj = (float*)qb;     // f32 [8192][768] == qb+kb bytes
    float*  part_w2   = (float*)hbf;    // f32 [8192][768] == hbf+attnb bytes

    dim3 rg(12, 12);
    repack_k<1><<<rg, 256, 0, stream>>>(wq,  WTqkv,                      768, 768, 768);
    repack_k<1><<<rg, 256, 0, stream>>>(wk,  WTqkv + (size_t)768*768,    768, 768, 768);
    repack_k<1><<<rg, 256, 0, stream>>>(wvw, WTqkv + (size_t)2*768*768,  768, 768, 768);
    repack_k<0><<<rg, 256, 0, stream>>>(wp,  WTp, 768, 768, 768);
    repack_k<0><<<dim3(48, 12), 256, 0, stream>>>(w1, WT1, 768, 3072, 768);
    repack_k<0><<<dim3(12, 48), 256, 0, stream>>>(w2, WT2, 3072, 768, 3072);

    // --- attention sublayer ---
    ln_k<<<MM, 256, 0, stream>>>(x, g1, be1, hbf);
    gemm8p<1><<<dim3(9, 32, 1), 512, 0, stream>>>(hbf, WTqkv, MM, 2304, CC,
        qb, kb, vb, bq, bk, bv, nullptr, nullptr, nullptr);
    vtrans_k<<<48 * 32, 256, 0, stream>>>(vb, vtb);
    attn_k<<<48 * 16, 256, 0, stream>>>(qb, kb, vtb, attnb);
    // proj: split-K=2, z=1 partial -> part_proj (qb region, dead after attn)
    gemm8p<2><<<dim3(3, 32, 2), 512, 0, stream>>>(attnb, WTp, MM, CC, CC,
        out, nullptr, nullptr, bp, nullptr, nullptr, x, nullptr, part_proj);

    // --- MLP sublayer (ln2 fuses the proj split-K reduce) ---
    ln_add_k<<<MM, 256, 0, stream>>>(out, part_proj, g2, be2, hbf);
    gemm8p<3><<<dim3(12, 32, 1), 512, 0, stream>>>(hbf, WT1, MM, C4, CC,
        nullptr, nullptr, nullptr, b1, nullptr, nullptr, nullptr, midb, nullptr);
    // w2: split-K=2, z=1 partial -> part_w2 (hbf/attnb region, dead after w1)
    gemm8p<2><<<dim3(3, 32, 2), 512, 0, stream>>>(midb, WT2, MM, CC, C4,
        out, nullptr, nullptr, b2, nullptr, nullptr, out, nullptr, part_w2);
    addto_k<<<2048, 256, 0, stream>>>(out, part_w2, MM * CC / 4);
}